// Round 1
// baseline (974.156 us; speedup 1.0000x reference)
//
#include <hip/hip_runtime.h>
#include <math.h>

// LSTM: B=512, T=1000, I=64, H=50, gates 4H=200 in torch order (i,f,g,o).
// One block per batch row; thread g in [0,200) owns gate g with its weight
// rows held in VGPRs; x_t and h broadcast via LDS; c held in registers of
// threads 0..49. Fused input GEMM (no xg materialization -> HBM = x only).

#define HSZ 50
#define ISZ 64
#define TSZ 1000
#define GSZ 200   // 4*HSZ

__device__ __forceinline__ float sigmoid_(float v) {
    return 1.0f / (1.0f + __expf(-v));
}
__device__ __forceinline__ float tanh_(float v) {
    // 1 - 2/(1+e^{2v}); saturates correctly at +/-1 for large |v|
    return 1.0f - 2.0f / (1.0f + __expf(2.0f * v));
}

__global__ __launch_bounds__(256, 2) void lstm_fused(
    const float* __restrict__ x,      // [B, T, I]
    const float* __restrict__ W_ih,   // [4H, I]
    const float* __restrict__ W_hh,   // [4H, H]
    const float* __restrict__ b_ih,   // [4H]
    const float* __restrict__ b_hh,   // [4H]
    const float* __restrict__ W_out,  // [2, H]
    const float* __restrict__ b_out,  // [2]
    float* __restrict__ out)          // [B, 2]
{
    const int b   = blockIdx.x;
    const int tid = threadIdx.x;

    __shared__ __align__(16) float xs[2][ISZ];   // double-buffered x_t
    __shared__ __align__(16) float hs[HSZ + 2];  // hidden state
    __shared__ __align__(16) float gs[GSZ];      // activated gates

    // --- Per-thread weights in registers (amortized over 1000 steps) ---
    float wih[ISZ];
    float whh[HSZ];
    float bias = 0.0f;
    if (tid < GSZ) {
        const float* wi = W_ih + tid * ISZ;
        #pragma unroll
        for (int i = 0; i < ISZ; ++i) wih[i] = wi[i];
        const float* wh = W_hh + tid * HSZ;
        #pragma unroll
        for (int j = 0; j < HSZ; ++j) whh[j] = wh[j];
        bias = b_ih[tid] + b_hh[tid];
    }

    float c_reg = 0.0f;                 // c[tid] for tid < HSZ
    if (tid < HSZ) hs[tid] = 0.0f;

    const float* xb = x + (size_t)b * (TSZ * ISZ);
    if (tid < ISZ) xs[0][tid] = xb[tid];
    __syncthreads();

    for (int t = 0; t < TSZ; ++t) {
        const int cur = t & 1;
        const int nxt = cur ^ 1;

        // Prefetch x[t+1] into registers (latency hides under gate compute)
        float xpre = 0.0f;
        const bool pf = (t + 1 < TSZ) && (tid < ISZ);
        if (pf) xpre = xb[(size_t)(t + 1) * ISZ + tid];

        if (tid < GSZ) {
            float acc = bias;
            const float4* x4 = (const float4*)(&xs[cur][0]);
            #pragma unroll
            for (int i = 0; i < ISZ / 4; ++i) {
                float4 v = x4[i];
                acc += v.x * wih[4 * i + 0];
                acc += v.y * wih[4 * i + 1];
                acc += v.z * wih[4 * i + 2];
                acc += v.w * wih[4 * i + 3];
            }
            const float4* h4 = (const float4*)(&hs[0]);
            #pragma unroll
            for (int j = 0; j < 12; ++j) {     // 48 of 50
                float4 v = h4[j];
                acc += v.x * whh[4 * j + 0];
                acc += v.y * whh[4 * j + 1];
                acc += v.z * whh[4 * j + 2];
                acc += v.w * whh[4 * j + 3];
            }
            acc += hs[48] * whh[48];
            acc += hs[49] * whh[49];

            // Activation: gates [0,100)=i,f sigmoid; [100,150)=g tanh; [150,200)=o sigmoid
            float a = (tid >= 2 * HSZ && tid < 3 * HSZ) ? tanh_(acc) : sigmoid_(acc);
            gs[tid] = a;
        }
        if (pf) xs[nxt][tid] = xpre;
        __syncthreads();   // gates + next-x visible

        if (tid < HSZ) {
            float ig = gs[tid];
            float fg = gs[tid + HSZ];
            float gg = gs[tid + 2 * HSZ];
            float og = gs[tid + 3 * HSZ];
            c_reg = fg * c_reg + ig * gg;
            hs[tid] = og * tanh_(c_reg);
        }
        __syncthreads();   // new h visible
    }

    // Final projection: out[b, k] = sum_j h[j] * W_out[k, j] + b_out[k]
    if (tid < 2) {
        float acc = b_out[tid];
        const float* wo = W_out + tid * HSZ;
        #pragma unroll
        for (int j = 0; j < HSZ; ++j) acc += hs[j] * wo[j];
        out[b * 2 + tid] = acc;
    }
}

extern "C" void kernel_launch(void* const* d_in, const int* in_sizes, int n_in,
                              void* d_out, int out_size, void* d_ws, size_t ws_size,
                              hipStream_t stream) {
    const float* x     = (const float*)d_in[0];
    const float* W_ih  = (const float*)d_in[1];
    const float* W_hh  = (const float*)d_in[2];
    const float* b_ih  = (const float*)d_in[3];
    const float* b_hh  = (const float*)d_in[4];
    const float* W_out = (const float*)d_in[5];
    const float* b_out = (const float*)d_in[6];
    float* out = (float*)d_out;

    const int B = in_sizes[0] / (TSZ * ISZ);   // 512
    hipLaunchKernelGGL(lstm_fused, dim3(B), dim3(256), 0, stream,
                       x, W_ih, W_hh, b_ih, b_hh, W_out, b_out, out);
}